// Round 1
// baseline (63.693 us; speedup 1.0000x reference)
//
#include <hip/hip_runtime.h>
#include <math.h>

// Reference math collapses: dist_map == 0 everywhere (every pixel is at
// distance 0 from its own set, and dist_map = min(d_to_zeros, d_to_ones)),
// so w == 1, max(w) == 1, final_weight == 1 + THETA == 6 exactly.
// loss = 6 * mean( softplus(pred) - pred*target )

#define N_TOTAL (8 * 256 * 256)   // 524288 elements
#define BLOCK 256
#define NVEC (N_TOTAL / 4)        // 131072 float4s
#define GRID (NVEC / BLOCK)       // 512 blocks

__global__ __launch_bounds__(BLOCK) void boundary_loss_kernel(
    const float* __restrict__ pred,
    const float* __restrict__ target,
    float* __restrict__ out)
{
    const int idx = blockIdx.x * BLOCK + threadIdx.x;
    const float4 p = reinterpret_cast<const float4*>(pred)[idx];
    const float4 t = reinterpret_cast<const float4*>(target)[idx];

    // stable softplus: logaddexp(0,x) = max(x,0) + log1p(exp(-|x|))
    float s;
    {
        float x;
        x = p.x; s  = fmaxf(x, 0.f) + log1pf(expf(-fabsf(x))) - x * t.x;
        x = p.y; s += fmaxf(x, 0.f) + log1pf(expf(-fabsf(x))) - x * t.y;
        x = p.z; s += fmaxf(x, 0.f) + log1pf(expf(-fabsf(x))) - x * t.z;
        x = p.w; s += fmaxf(x, 0.f) + log1pf(expf(-fabsf(x))) - x * t.w;
    }

    // wave-64 reduction
    #pragma unroll
    for (int off = 32; off > 0; off >>= 1)
        s += __shfl_down(s, off, 64);

    __shared__ float lds[BLOCK / 64];
    const int lane = threadIdx.x & 63;
    const int wave = threadIdx.x >> 6;
    if (lane == 0) lds[wave] = s;
    __syncthreads();

    if (threadIdx.x == 0) {
        float tot = lds[0] + lds[1] + lds[2] + lds[3];
        // scale per-block so the atomic accumulates the final answer directly
        atomicAdd(out, tot * (6.0f / (float)N_TOTAL));
    }
}

extern "C" void kernel_launch(void* const* d_in, const int* in_sizes, int n_in,
                              void* d_out, int out_size, void* d_ws, size_t ws_size,
                              hipStream_t stream)
{
    const float* pred   = (const float*)d_in[0];
    const float* target = (const float*)d_in[1];
    float* out = (float*)d_out;

    // d_out is re-poisoned to 0xAA before every timed replay — zero it here.
    hipMemsetAsync(out, 0, sizeof(float), stream);

    boundary_loss_kernel<<<GRID, BLOCK, 0, stream>>>(pred, target, out);
}